// Round 9
// baseline (5298.771 us; speedup 1.0000x reference)
//
#include <hip/hip_runtime.h>
#include <hip/hip_bf16.h>

// BiLSTM-CRF forward: B=32, T=512, E=512, H=256 (per dir), 4H=1024, K=12
// Inputs: fp32 (+ int32 sentence). Outputs fp32:
//   [0,1024)      path_score [32][32]
//   [1024,17408)  best_path  [32][512] (tags as fp32)
// R16 = R15 skeleton with the exchange protocol replaced by TAGGED WORDS:
//   hx is u64 per unit: (tag<<32)|(bf16hi<<16|bf16lo), tag = h-index
//   (consumed at step s expects tag s; h0 path covers s=0; memset-0 each
//   launch => stale tags never match => re-poison safe).
//   Producer: 8 u64 relaxed agent stores. NO vmcnt drain, NO flag store.
//   Consumer: load 32 words, check tags, per-word retry (load IS the poll).
//   Removes 2 of 3 serialized agent-scope RTs per step.
//   Overwrite safety (2 parity buffers): a wave writing tag s+2 into buffer
//   s&1 first validated ALL tag-s+1 words, which each wave wrote only after
//   finishing its step-s reads (closed by the per-step block barrier).
// Everything else identical to R15 (LDS staging + perm unpack, one barrier
// per step, xvA/xvB named double buffers, strength-reduced addressing).
// Numerics bit-identical. Lessons kept: R9 sc0 scope bug; R11 1MB-stride
// mailbox; R13 phase-split; R14 >1 wave/SIMD spills.

typedef __attribute__((ext_vector_type(8))) __bf16 bf16x8;
typedef __attribute__((ext_vector_type(4))) float  f32x4;
typedef __attribute__((ext_vector_type(4))) unsigned int u32x4;

#define MFMA16(a, b, c) __builtin_amdgcn_mfma_f32_16x16x32_bf16((a), (b), (c), 0, 0, 0)

__device__ __forceinline__ float sigm(float x) { return 1.0f / (1.0f + __expf(-x)); }
__device__ __forceinline__ float tanh_f(float x) {
  x = fminf(fmaxf(x, -15.0f), 15.0f);
  float e = __expf(2.0f * x);
  return (e - 1.0f) / (e + 1.0f);
}

__device__ __forceinline__ void split8(const float* v, bf16x8& hi, bf16x8& lo) {
#pragma unroll
  for (int j = 0; j < 8; j++) {
    __bf16 h = (__bf16)v[j];
    hi[j] = h;
    lo[j] = (__bf16)(v[j] - (float)h);
  }
}

// ---------------------------------------------------------------------------
// Kernel 1: xg[m=(b,t)][n=(dir,gate,unit)] = embed[sent[m]].w_ih[n] + bias[n]
// M=16384, N=2048, K=512. 128x128 tile/WG, 4 waves 2x2, 3-term hi/lo MFMA.
// ---------------------------------------------------------------------------
__global__ __launch_bounds__(256) void xg_gemm(
    const int* __restrict__ sent, const float* __restrict__ embed,
    const float* __restrict__ wih_f, const float* __restrict__ wih_b,
    const float* __restrict__ bias_f, const float* __restrict__ bias_b,
    float* __restrict__ xg)
{
  __shared__ __bf16 Ah[128][40], Al[128][40];  // 32 k + 8 pad
  __shared__ __bf16 Bh[128][40], Bl[128][40];
  __shared__ int toks[128];
  const int tid = threadIdx.x;
  const int m0 = blockIdx.x * 128, n0 = blockIdx.y * 128;
  if (tid < 128) toks[tid] = sent[m0 + tid];
  const int wave = tid >> 6, lane = tid & 63, q = lane >> 4, c = lane & 15;
  const int wy = wave >> 1, wx = wave & 1;
  f32x4 acc[4][4];
  for (int mt = 0; mt < 4; mt++)
    for (int nt = 0; nt < 4; nt++)
      acc[mt][nt] = f32x4{0.0f, 0.0f, 0.0f, 0.0f};
  __syncthreads();

  for (int k0 = 0; k0 < 512; k0 += 32) {
#pragma unroll
    for (int i = 0; i < 2; i++) {
      int ch = tid + (i << 8);
      int r = ch >> 2, kc = ch & 3;
      float tmp[8];
      const float* asrc = embed + (size_t)toks[r] * 512 + k0 + kc * 8;
#pragma unroll
      for (int j = 0; j < 8; j++) tmp[j] = asrc[j];
      bf16x8 hi, lo;
      split8(tmp, hi, lo);
      *(bf16x8*)&Ah[r][kc * 8] = hi;
      *(bf16x8*)&Al[r][kc * 8] = lo;
      int n = n0 + r;
      const float* wsrc = (n < 1024) ? (wih_f + (size_t)n * 512)
                                     : (wih_b + (size_t)(n - 1024) * 512);
#pragma unroll
      for (int j = 0; j < 8; j++) tmp[j] = wsrc[k0 + kc * 8 + j];
      split8(tmp, hi, lo);
      *(bf16x8*)&Bh[r][kc * 8] = hi;
      *(bf16x8*)&Bl[r][kc * 8] = lo;
    }
    __syncthreads();
    bf16x8 ah[4], al[4], bh[4], bl[4];
#pragma unroll
    for (int t4 = 0; t4 < 4; t4++) {
      int ar = wy * 64 + t4 * 16 + c, br = wx * 64 + t4 * 16 + c;
      ah[t4] = *(const bf16x8*)&Ah[ar][q * 8];
      al[t4] = *(const bf16x8*)&Al[ar][q * 8];
      bh[t4] = *(const bf16x8*)&Bh[br][q * 8];
      bl[t4] = *(const bf16x8*)&Bl[br][q * 8];
    }
#pragma unroll
    for (int mt = 0; mt < 4; mt++)
#pragma unroll
      for (int nt = 0; nt < 4; nt++) {
        acc[mt][nt] = MFMA16(ah[mt], bh[nt], acc[mt][nt]);
        acc[mt][nt] = MFMA16(al[mt], bh[nt], acc[mt][nt]);
        acc[mt][nt] = MFMA16(ah[mt], bl[nt], acc[mt][nt]);
      }
    __syncthreads();
  }

#pragma unroll
  for (int nt = 0; nt < 4; nt++) {
    int n = n0 + wx * 64 + nt * 16 + c;
    float bval = (n < 1024) ? bias_f[n] : bias_b[n - 1024];
#pragma unroll
    for (int mt = 0; mt < 4; mt++) {
      int mbase = m0 + wy * 64 + mt * 16 + q * 4;
#pragma unroll
      for (int reg = 0; reg < 4; reg++)
        xg[(size_t)(mbase + reg) * 2048 + n] = acc[mt][nt][reg] + bval;
    }
  }
}

// ---------------------------------------------------------------------------
// Kernel 2: both LSTM recurrences. 8 blocks: blk = d*4 + hs. Tagged exchange.
// ---------------------------------------------------------------------------
__global__ __launch_bounds__(256, 1) void lstm_rec(
    const float* __restrict__ xg,
    const float* __restrict__ whh_f, const float* __restrict__ whh_b,
    const float* __restrict__ h0, const float* __restrict__ c0,
    float* __restrict__ h_seq,            // [32][512][512]: 0-255 fwd, 256-511 bwd
    unsigned long long* __restrict__ hx)  // [dir][parity][32][256] tagged u64
{
  const int blk = blockIdx.x;
  const int d = blk >> 2, hs = blk & 3;
  const int tid = threadIdx.x;
  const int wave = tid >> 6, lane = tid & 63, q = lane >> 4, c = lane & 15;
  const float* __restrict__ whh = d ? whh_b : whh_f;

  __shared__ __bf16 hfrag[2][2][16][512];  // [parity][hi/lo][frag][xor-swizzled]

  bf16x8 wfh[4][8], wfl[4][8];
#pragma unroll
  for (int g = 0; g < 4; g++) {
    int row = g * 256 + hs * 64 + wave * 16 + c;   // w_hh row (gate-major)
    const float* wr = whh + (size_t)row * 256;
#pragma unroll
    for (int ks = 0; ks < 8; ks++) {
      float tmp[8];
#pragma unroll
      for (int j = 0; j < 8; j++) tmp[j] = wr[ks * 32 + q * 8 + j];
      split8(tmp, wfh[g][ks], wfl[g][ks]);
    }
  }
  const int ug = hs * 64 + wave * 16 + c;
  float cst[2][4];
#pragma unroll
  for (int mt = 0; mt < 2; mt++)
#pragma unroll
    for (int reg = 0; reg < 4; reg++)
      cst[mt][reg] = c0[d * 8192 + (mt * 16 + q * 4 + reg) * 256 + ug];

  const int sb = tid >> 3;            // staging: batch row
  const int kc4 = (tid & 7) * 4;      // staging: first 8-elem chunk

  // staging LDS indices are per-thread constants
  int fid_c[4], pos_c[4];
#pragma unroll
  for (int i = 0; i < 4; i++) {
    int kc = kc4 + i;
    fid_c[i] = ((sb >> 4) << 3) + (kc >> 2);
    pos_c[i] = ((((kc & 3) << 4) + (sb & 15)) ^ (fid_c[i] & 7));
  }

  // exchange read bases (per parity), u64 per unit
  const unsigned long long* hb64p[2];
  hb64p[0] = hx + ((size_t)((d * 2 + 0) * 32 + sb)) * 256 + kc4 * 8;
  hb64p[1] = hx + ((size_t)((d * 2 + 1) * 32 + sb)) * 256 + kc4 * 8;
  // exchange write bases (per parity) + per-(mt,reg) batch offsets
  const int hwbase0 = (d * 2 + 0) * 32 * 256 + ug;
  const int hwbase1 = (d * 2 + 1) * 32 * 256 + ug;
  int bof[2][4];
#pragma unroll
  for (int mt = 0; mt < 2; mt++)
#pragma unroll
    for (int reg = 0; reg < 4; reg++)
      bof[mt][reg] = (mt * 16 + q * 4 + reg) * 256;

  const int t0 = d ? 511 : 0;
  const int tdelt = d ? -2048 : 2048;        // xg element-offset delta per step
  const int sdelt = d ? -512 : 512;          // h_seq element-offset delta per step

  int xgo[2][4], hso[2][4];
#pragma unroll
  for (int mt = 0; mt < 2; mt++)
#pragma unroll
    for (int reg = 0; reg < 4; reg++) {
      int b = mt * 16 + q * 4 + reg;
      xgo[mt][reg] = (b * 512 + t0) * 2048 + (d << 10) + ug;
      hso[mt][reg] = (b * 512 + t0) * 512 + (d << 8) + ug;
    }

  float xvA[2][4][4], xvB[2][4][4];
#pragma unroll
  for (int mt = 0; mt < 2; mt++)
#pragma unroll
    for (int reg = 0; reg < 4; reg++)
#pragma unroll
      for (int g = 0; g < 4; g++)
        xvA[mt][g][reg] = xg[xgo[mt][reg] + (g << 8)];

#define LSTM_STEP(S_, P_, XC_, XN_)                                           \
  {                                                                           \
    if ((S_) == 0) {                                                          \
      _Pragma("unroll")                                                       \
      for (int i = 0; i < 4; i++) {                                           \
        int kc = kc4 + i;                                                     \
        float tmp[8];                                                         \
        const float* src = h0 + d * 8192 + sb * 256 + kc * 8;                 \
        _Pragma("unroll")                                                     \
        for (int j = 0; j < 8; j++) tmp[j] = src[j];                          \
        bf16x8 vhi, vlo;                                                      \
        split8(tmp, vhi, vlo);                                                \
        *(bf16x8*)&hfrag[0][0][fid_c[i]][pos_c[i] * 8] = vhi;                 \
        *(bf16x8*)&hfrag[0][1][fid_c[i]][pos_c[i] * 8] = vlo;                 \
      }                                                                       \
    } else {                                                                  \
      const unsigned int tagw = (unsigned int)(S_);                           \
      const unsigned long long* hb = hb64p[P_];                               \
      _Pragma("unroll")                                                       \
      for (int r2 = 0; r2 < 2; r2++) {                                        \
        unsigned long long v[16];                                             \
        _Pragma("unroll")                                                     \
        for (int i = 0; i < 16; i++)                                          \
          v[i] = __hip_atomic_load(hb + r2 * 16 + i, __ATOMIC_RELAXED,        \
                                   __HIP_MEMORY_SCOPE_AGENT);                 \
        while (true) {                                                        \
          unsigned int bad = 0;                                               \
          _Pragma("unroll")                                                   \
          for (int i = 0; i < 16; i++)                                        \
            bad |= ((unsigned int)(v[i] >> 32)) ^ tagw;                       \
          if (__all(bad == 0)) break;                                         \
          __builtin_amdgcn_s_sleep(1);                                        \
          _Pragma("unroll")                                                   \
          for (int i = 0; i < 16; i++)                                        \
            if (((unsigned int)(v[i] >> 32)) != tagw)                         \
              v[i] = __hip_atomic_load(hb + r2 * 16 + i, __ATOMIC_RELAXED,    \
                                       __HIP_MEMORY_SCOPE_AGENT);             \
        }                                                                     \
        _Pragma("unroll")                                                     \
        for (int i2 = 0; i2 < 2; i2++) {                                      \
          int ci = r2 * 2 + i2;                                               \
          u32x4 vh, vl;                                                       \
          _Pragma("unroll")                                                   \
          for (int k = 0; k < 4; k++) {                                       \
            unsigned int a0 = (unsigned int)v[i2 * 8 + 2 * k];                \
            unsigned int a1 = (unsigned int)v[i2 * 8 + 2 * k + 1];            \
            vh[k] = __builtin_amdgcn_perm(a1, a0, 0x07060302u);               \
            vl[k] = __builtin_amdgcn_perm(a1, a0, 0x05040100u);               \
          }                                                                   \
          *(u32x4*)&hfrag[P_][0][fid_c[ci]][pos_c[ci] * 8] = vh;              \
          *(u32x4*)&hfrag[P_][1][fid_c[ci]][pos_c[ci] * 8] = vl;              \
        }                                                                     \
      }                                                                       \
    }                                                                         \
    f32x4 acc[2][4];                                                          \
    _Pragma("unroll")                                                         \
    for (int mt = 0; mt < 2; mt++)                                            \
      _Pragma("unroll")                                                       \
      for (int g = 0; g < 4; g++)                                             \
        _Pragma("unroll")                                                     \
        for (int reg = 0; reg < 4; reg++)                                     \
          acc[mt][g][reg] = XC_[mt][g][reg];                                  \
    __syncthreads();                                                          \
    _Pragma("unroll")                                                         \
    for (int ks = 0; ks < 8; ks++) {                                          \
      int pos = (lane ^ ks) * 8;                                              \
      bf16x8 ahi0 = *(const bf16x8*)&hfrag[P_][0][ks][pos];                   \
      bf16x8 ahi1 = *(const bf16x8*)&hfrag[P_][0][8 + ks][pos];               \
      bf16x8 alo0 = *(const bf16x8*)&hfrag[P_][1][ks][pos];                   \
      bf16x8 alo1 = *(const bf16x8*)&hfrag[P_][1][8 + ks][pos];               \
      _Pragma("unroll")                                                       \
      for (int g = 0; g < 4; g++) {                                           \
        acc[0][g] = MFMA16(ahi0, wfh[g][ks], acc[0][g]);                      \
        acc[1][g] = MFMA16(ahi1, wfh[g][ks], acc[1][g]);                      \
        acc[0][g] = MFMA16(alo0, wfh[g][ks], acc[0][g]);                      \
        acc[1][g] = MFMA16(alo1, wfh[g][ks], acc[1][g]);                      \
        acc[0][g] = MFMA16(ahi0, wfl[g][ks], acc[0][g]);                      \
        acc[1][g] = MFMA16(ahi1, wfl[g][ks], acc[1][g]);                      \
      }                                                                       \
    }                                                                         \
    const unsigned long long tagst = ((unsigned long long)((S_) + 1)) << 32;  \
    float hv[2][4];                                                           \
    _Pragma("unroll")                                                         \
    for (int mt = 0; mt < 2; mt++)                                            \
      _Pragma("unroll")                                                       \
      for (int reg = 0; reg < 4; reg++) {                                     \
        float iv = sigm(acc[mt][0][reg]);                                     \
        float fg = sigm(acc[mt][1][reg]);                                     \
        float gv = tanh_f(acc[mt][2][reg]);                                   \
        float ov = sigm(acc[mt][3][reg]);                                     \
        float cn = fg * cst[mt][reg] + iv * gv;                               \
        cst[mt][reg] = cn;                                                    \
        float hn = ov * tanh_f(cn);                                           \
        hv[mt][reg] = hn;                                                     \
        __bf16 hhi = (__bf16)hn;                                              \
        __bf16 hlo = (__bf16)(hn - (float)hhi);                               \
        unsigned int pack =                                                   \
            ((unsigned int)__builtin_bit_cast(unsigned short, hhi) << 16) |   \
            (unsigned int)__builtin_bit_cast(unsigned short, hlo);            \
        __hip_atomic_store(hx + ((P_) ? hwbase0 : hwbase1) + bof[mt][reg],    \
                           tagst | (unsigned long long)pack,                  \
                           __ATOMIC_RELAXED, __HIP_MEMORY_SCOPE_AGENT);       \
      }                                                                       \
    _Pragma("unroll")                                                         \
    for (int mt = 0; mt < 2; mt++)                                            \
      _Pragma("unroll")                                                       \
      for (int reg = 0; reg < 4; reg++)                                       \
        h_seq[hso[mt][reg]] = hv[mt][reg];                                    \
    if ((S_) < 511) {                                                         \
      _Pragma("unroll")                                                       \
      for (int mt = 0; mt < 2; mt++)                                          \
        _Pragma("unroll")                                                     \
        for (int reg = 0; reg < 4; reg++) {                                   \
          xgo[mt][reg] += tdelt;                                              \
          hso[mt][reg] += sdelt;                                              \
        }                                                                     \
      _Pragma("unroll")                                                       \
      for (int mt = 0; mt < 2; mt++)                                          \
        _Pragma("unroll")                                                     \
        for (int reg = 0; reg < 4; reg++)                                     \
          _Pragma("unroll")                                                   \
          for (int g = 0; g < 4; g++)                                         \
            XN_[mt][g][reg] = xg[xgo[mt][reg] + (g << 8)];                    \
    }                                                                         \
  }

  for (int s = 0; s < 512; s += 2) {
    LSTM_STEP(s,     0, xvA, xvB);
    LSTM_STEP(s + 1, 1, xvB, xvA);
  }
#undef LSTM_STEP
}

// ---------------------------------------------------------------------------
// Kernel 3: feats[m][k] = h_seq[m][:] . W_out[k][:] + b_out[k]   (fp32)
// ---------------------------------------------------------------------------
__global__ __launch_bounds__(256) void feats_k(
    const float* __restrict__ h_seq, const float* __restrict__ W_out,
    const float* __restrict__ b_out, float* __restrict__ feats)
{
  int m = blockIdx.x * 4 + (threadIdx.x >> 6);
  int lane = threadIdx.x & 63;
  const float4* hp = (const float4*)(h_seq + (size_t)m * 512 + lane * 8);
  float4 a = hp[0], b2 = hp[1];
  float h[8] = {a.x, a.y, a.z, a.w, b2.x, b2.y, b2.z, b2.w};
#pragma unroll
  for (int k = 0; k < 12; k++) {
    const float4* wp = (const float4*)(W_out + k * 512 + lane * 8);
    float4 w0 = wp[0], w1 = wp[1];
    float w[8] = {w0.x, w0.y, w0.z, w0.w, w1.x, w1.y, w1.z, w1.w};
    float p = 0.0f;
#pragma unroll
    for (int j = 0; j < 8; j++) p += h[j] * w[j];
#pragma unroll
    for (int off = 32; off > 0; off >>= 1) p += __shfl_xor(p, off);
    if (lane == 0) feats[(size_t)m * 12 + k] = p + b_out[k];
  }
}

// ---------------------------------------------------------------------------
// Kernel 4: Viterbi per batch (one wave). First-max tie-break == jnp.argmax.
// ---------------------------------------------------------------------------
__global__ __launch_bounds__(64) void viterbi_k(
    const float* __restrict__ feats, const float* __restrict__ trans,
    float* __restrict__ terminal, int* __restrict__ best,
    float* __restrict__ out_path)
{
  const int b = blockIdx.x;
  const int lane = threadIdx.x;
  __shared__ unsigned char bp[512][12];
  float trow[12];
#pragma unroll
  for (int pv = 0; pv < 12; pv++)
    trow[pv] = (lane < 12) ? trans[lane * 12 + pv] : -10000.0f;
  float fv = (lane == 10) ? 0.0f : -10000.0f;   // START = 10
  for (int t = 0; t < 512; t++) {
    float bestv = -3.4e38f;
    int arg = 0;
#pragma unroll
    for (int pv = 0; pv < 12; pv++) {
      float sc = __shfl(fv, pv) + trow[pv];
      if (sc > bestv) { bestv = sc; arg = pv; }   // strict > keeps first max
    }
    float ft = (lane < 12) ? feats[(size_t)(b * 512 + t) * 12 + lane] : 0.0f;
    if (lane < 12) {
      bp[t][lane] = (unsigned char)arg;
      fv = bestv + ft;
    }
  }
  float term = fv + ((lane < 12) ? trans[11 * 12 + lane] : 0.0f);  // STOP = 11
  if (lane < 12) terminal[b * 12 + lane] = term;
  float v = (lane < 12) ? term : -3.4e38f;
  int idx = lane;
#pragma unroll
  for (int off = 8; off > 0; off >>= 1) {
    float ov = __shfl_down(v, off);
    int oi = __shfl_down(idx, off);
    if (ov > v || (ov == v && oi < idx)) { v = ov; idx = oi; }
  }
  int bidx = __shfl(idx, 0);
  __syncthreads();
  if (lane == 0) {
    best[b] = bidx;
    int tag = bidx;
    out_path[b * 512 + 511] = (float)bidx;
    for (int t = 511; t >= 1; t--) {
      tag = bp[t][tag];
      out_path[b * 512 + t - 1] = (float)tag;
    }
  }
}

// ---------------------------------------------------------------------------
// Kernel 5: path_score[i][j] = terminal[i][best[j]]
// ---------------------------------------------------------------------------
__global__ __launch_bounds__(256) void pscore_k(
    const float* __restrict__ terminal, const int* __restrict__ best,
    float* __restrict__ out)
{
  int idx = blockIdx.x * 256 + threadIdx.x;
  if (idx < 1024) {
    int i = idx >> 5, j = idx & 31;
    out[idx] = terminal[i * 12 + best[j]];
  }
}

// ---------------------------------------------------------------------------
extern "C" void kernel_launch(void* const* d_in, const int* in_sizes, int n_in,
                              void* d_out, int out_size, void* d_ws, size_t ws_size,
                              hipStream_t stream)
{
  const int*   sent  = (const int*)d_in[0];
  const float* embed = (const float*)d_in[1];
  const float* wih_f = (const float*)d_in[2];
  const float* whh_f = (const float*)d_in[3];
  const float* b_f   = (const float*)d_in[4];
  const float* wih_b = (const float*)d_in[5];
  const float* whh_b = (const float*)d_in[6];
  const float* b_b   = (const float*)d_in[7];
  const float* h0    = (const float*)d_in[8];
  const float* c0    = (const float*)d_in[9];
  const float* W_out = (const float*)d_in[10];
  const float* b_out = (const float*)d_in[11];
  const float* trans = (const float*)d_in[12];

  char* ws = (char*)d_ws;
  float*              xg    = (float*)(ws);                    // 134217728 B
  float*              h_seq = (float*)(ws + 134217728);        //  33554432 B
  float*              feats = (float*)(ws + 167772160);        //    786432 B
  // hx overlays the feats region (524288 B <= 786432 B): hx is dead before
  // feats_k runs (stream order), so workspace footprint is unchanged.
  unsigned long long* hx    = (unsigned long long*)(ws + 167772160);
  float*              term  = (float*)(ws + 168693760);        //      1536 B
  int*                best  = (int*)(ws + 168695296);          //       128 B

  float* outp = (float*)d_out;

  // zero all tags: wanted tags are 1..512; 0 never matches => re-poison safe
  hipMemsetAsync(hx, 0, 2 * 2 * 32 * 256 * sizeof(unsigned long long), stream);
  xg_gemm<<<dim3(128, 16), 256, 0, stream>>>(sent, embed, wih_f, wih_b, b_f, b_b, xg);
  lstm_rec<<<8, 256, 0, stream>>>(xg, whh_f, whh_b, h0, c0, h_seq, hx);
  feats_k<<<4096, 256, 0, stream>>>(h_seq, W_out, b_out, feats);
  viterbi_k<<<32, 64, 0, stream>>>(feats, trans, term, best, outp + 1024);
  pscore_k<<<4, 256, 0, stream>>>(term, best, outp);
}

// Round 10
// 4147.206 us; speedup vs baseline: 1.2777x; 1.2777x over previous
//
#include <hip/hip_runtime.h>
#include <hip/hip_bf16.h>

// BiLSTM-CRF forward: B=32, T=512, E=512, H=256 (per dir), 4H=1024, K=12
// Inputs: fp32 (+ int32 sentence). Outputs fp32:
//   [0,1024)      path_score [32][32]
//   [1024,17408)  best_path  [32][512] (tags as fp32)
// R17 = R15 skeleton (validated 3398us) with ONE change: the per-step vmem
// issue order is rearranged so the flag poll starts with an EMPTY vmem
// queue. R15 issued [flag store, 8 h_seq HBM stores, 32 xg HBM loads] right
// before the next poll; the poll's s_waitcnt vmcnt(0) then drained the FULL
// xg HBM latency + h_seq store acks every step, on the critical path.
// New order: poll (clean) -> hx data loads -> unpack+stage (waits only the
// data) -> store PREVIOUS step's h (hv carried in regs; h_seq has no
// intra-kernel consumer) -> issue xg prefetch for s+1 -> barrier -> MFMA ->
// epilogue -> hx stores -> vmcnt(0) -> flag. xg/h_seq drain under MFMA.
// Exchange protocol byte-identical to R15/R12. Numerics bit-identical.
// Lessons kept: tagged-word exchange falsified twice (R8/R16 — flag+bulk
// wins); R9 sc0 scope; R11 1MB-stride mailbox; R13 phase-split; R14
// >1 wave/SIMD spills.

typedef __attribute__((ext_vector_type(8))) __bf16 bf16x8;
typedef __attribute__((ext_vector_type(4))) float  f32x4;
typedef __attribute__((ext_vector_type(4))) unsigned int u32x4;

#define MFMA16(a, b, c) __builtin_amdgcn_mfma_f32_16x16x32_bf16((a), (b), (c), 0, 0, 0)

__device__ __forceinline__ float sigm(float x) { return 1.0f / (1.0f + __expf(-x)); }
__device__ __forceinline__ float tanh_f(float x) {
  x = fminf(fmaxf(x, -15.0f), 15.0f);
  float e = __expf(2.0f * x);
  return (e - 1.0f) / (e + 1.0f);
}

__device__ __forceinline__ void split8(const float* v, bf16x8& hi, bf16x8& lo) {
#pragma unroll
  for (int j = 0; j < 8; j++) {
    __bf16 h = (__bf16)v[j];
    hi[j] = h;
    lo[j] = (__bf16)(v[j] - (float)h);
  }
}

// ---------------------------------------------------------------------------
// Kernel 1: xg[m=(b,t)][n=(dir,gate,unit)] = embed[sent[m]].w_ih[n] + bias[n]
// M=16384, N=2048, K=512. 128x128 tile/WG, 4 waves 2x2, 3-term hi/lo MFMA.
// ---------------------------------------------------------------------------
__global__ __launch_bounds__(256) void xg_gemm(
    const int* __restrict__ sent, const float* __restrict__ embed,
    const float* __restrict__ wih_f, const float* __restrict__ wih_b,
    const float* __restrict__ bias_f, const float* __restrict__ bias_b,
    float* __restrict__ xg)
{
  __shared__ __bf16 Ah[128][40], Al[128][40];  // 32 k + 8 pad
  __shared__ __bf16 Bh[128][40], Bl[128][40];
  __shared__ int toks[128];
  const int tid = threadIdx.x;
  const int m0 = blockIdx.x * 128, n0 = blockIdx.y * 128;
  if (tid < 128) toks[tid] = sent[m0 + tid];
  const int wave = tid >> 6, lane = tid & 63, q = lane >> 4, c = lane & 15;
  const int wy = wave >> 1, wx = wave & 1;
  f32x4 acc[4][4];
  for (int mt = 0; mt < 4; mt++)
    for (int nt = 0; nt < 4; nt++)
      acc[mt][nt] = f32x4{0.0f, 0.0f, 0.0f, 0.0f};
  __syncthreads();

  for (int k0 = 0; k0 < 512; k0 += 32) {
#pragma unroll
    for (int i = 0; i < 2; i++) {
      int ch = tid + (i << 8);
      int r = ch >> 2, kc = ch & 3;
      float tmp[8];
      const float* asrc = embed + (size_t)toks[r] * 512 + k0 + kc * 8;
#pragma unroll
      for (int j = 0; j < 8; j++) tmp[j] = asrc[j];
      bf16x8 hi, lo;
      split8(tmp, hi, lo);
      *(bf16x8*)&Ah[r][kc * 8] = hi;
      *(bf16x8*)&Al[r][kc * 8] = lo;
      int n = n0 + r;
      const float* wsrc = (n < 1024) ? (wih_f + (size_t)n * 512)
                                     : (wih_b + (size_t)(n - 1024) * 512);
#pragma unroll
      for (int j = 0; j < 8; j++) tmp[j] = wsrc[k0 + kc * 8 + j];
      split8(tmp, hi, lo);
      *(bf16x8*)&Bh[r][kc * 8] = hi;
      *(bf16x8*)&Bl[r][kc * 8] = lo;
    }
    __syncthreads();
    bf16x8 ah[4], al[4], bh[4], bl[4];
#pragma unroll
    for (int t4 = 0; t4 < 4; t4++) {
      int ar = wy * 64 + t4 * 16 + c, br = wx * 64 + t4 * 16 + c;
      ah[t4] = *(const bf16x8*)&Ah[ar][q * 8];
      al[t4] = *(const bf16x8*)&Al[ar][q * 8];
      bh[t4] = *(const bf16x8*)&Bh[br][q * 8];
      bl[t4] = *(const bf16x8*)&Bl[br][q * 8];
    }
#pragma unroll
    for (int mt = 0; mt < 4; mt++)
#pragma unroll
      for (int nt = 0; nt < 4; nt++) {
        acc[mt][nt] = MFMA16(ah[mt], bh[nt], acc[mt][nt]);
        acc[mt][nt] = MFMA16(al[mt], bh[nt], acc[mt][nt]);
        acc[mt][nt] = MFMA16(ah[mt], bl[nt], acc[mt][nt]);
      }
    __syncthreads();
  }

#pragma unroll
  for (int nt = 0; nt < 4; nt++) {
    int n = n0 + wx * 64 + nt * 16 + c;
    float bval = (n < 1024) ? bias_f[n] : bias_b[n - 1024];
#pragma unroll
    for (int mt = 0; mt < 4; mt++) {
      int mbase = m0 + wy * 64 + mt * 16 + q * 4;
#pragma unroll
      for (int reg = 0; reg < 4; reg++)
        xg[(size_t)(mbase + reg) * 2048 + n] = acc[mt][nt][reg] + bval;
    }
  }
}

// ---------------------------------------------------------------------------
// Kernel 2: both LSTM recurrences. 8 blocks: blk = d*4 + hs. R12 protocol,
// R17 issue order (poll on empty vmem queue).
// ---------------------------------------------------------------------------
__global__ __launch_bounds__(256, 1) void lstm_rec(
    const float* __restrict__ xg,
    const float* __restrict__ whh_f, const float* __restrict__ whh_b,
    const float* __restrict__ h0, const float* __restrict__ c0,
    float* __restrict__ h_seq,     // [32][512][512]: cols 0-255 fwd, 256-511 bwd
    unsigned int* __restrict__ hx, // [dir][parity][32][256] packed hi/lo bf16
    int* __restrict__ flags)       // [dir][step][16 waves]
{
  const int blk = blockIdx.x;
  const int d = blk >> 2, hs = blk & 3;
  const int tid = threadIdx.x;
  const int wave = tid >> 6, lane = tid & 63, q = lane >> 4, c = lane & 15;
  const float* __restrict__ whh = d ? whh_b : whh_f;

  __shared__ __bf16 hfrag[2][2][16][512];  // [parity][hi/lo][frag][xor-swizzled]

  bf16x8 wfh[4][8], wfl[4][8];
#pragma unroll
  for (int g = 0; g < 4; g++) {
    int row = g * 256 + hs * 64 + wave * 16 + c;   // w_hh row (gate-major)
    const float* wr = whh + (size_t)row * 256;
#pragma unroll
    for (int ks = 0; ks < 8; ks++) {
      float tmp[8];
#pragma unroll
      for (int j = 0; j < 8; j++) tmp[j] = wr[ks * 32 + q * 8 + j];
      split8(tmp, wfh[g][ks], wfl[g][ks]);
    }
  }
  const int ug = hs * 64 + wave * 16 + c;
  float cst[2][4];
#pragma unroll
  for (int mt = 0; mt < 2; mt++)
#pragma unroll
    for (int reg = 0; reg < 4; reg++)
      cst[mt][reg] = c0[d * 8192 + (mt * 16 + q * 4 + reg) * 256 + ug];

  const int sb = tid >> 3;            // staging: batch row
  const int kc4 = (tid & 7) * 4;      // staging: first 8-elem chunk

  // staging LDS indices are per-thread constants
  int fid_c[4], pos_c[4];
#pragma unroll
  for (int i = 0; i < 4; i++) {
    int kc = kc4 + i;
    fid_c[i] = ((sb >> 4) << 3) + (kc >> 2);
    pos_c[i] = ((((kc & 3) << 4) + (sb & 15)) ^ (fid_c[i] & 7));
  }

  // exchange read bases (per parity)
  const unsigned long long* hb64p[2];
  hb64p[0] = (const unsigned long long*)(hx + ((size_t)((d * 2 + 0) * 32 + sb)) * 256 + kc4 * 8);
  hb64p[1] = (const unsigned long long*)(hx + ((size_t)((d * 2 + 1) * 32 + sb)) * 256 + kc4 * 8);
  // exchange write bases (per parity) + per-(mt,reg) batch offsets
  const int hwbase0 = (d * 2 + 0) * 32 * 256 + ug;
  const int hwbase1 = (d * 2 + 1) * 32 * 256 + ug;
  int bof[2][4];
#pragma unroll
  for (int mt = 0; mt < 2; mt++)
#pragma unroll
    for (int reg = 0; reg < 4; reg++)
      bof[mt][reg] = (mt * 16 + q * 4 + reg) * 256;

  int fro = (d * 512) * 16 + (lane & 15);    // flag line polled at step s (holds s-1)
  int fwo = (d * 512) * 16 + hs * 4 + wave;  // flag word written at step s

  const int t0 = d ? 511 : 0;
  const int tdelt = d ? -2048 : 2048;        // xg element-offset delta per step
  const int sdelt = d ? -512 : 512;          // h_seq element-offset delta per step

  int xgo[2][4], hso[2][4];
#pragma unroll
  for (int mt = 0; mt < 2; mt++)
#pragma unroll
    for (int reg = 0; reg < 4; reg++) {
      int b = mt * 16 + q * 4 + reg;
      xgo[mt][reg] = (b * 512 + t0) * 2048 + (d << 10) + ug;
      hso[mt][reg] = (b * 512 + t0) * 512 + (d << 8) + ug;
    }

  float xvA[2][4][4], xvB[2][4][4];
  float hvp[2][4];                           // previous step's h, carried in regs
#pragma unroll
  for (int mt = 0; mt < 2; mt++)
#pragma unroll
    for (int reg = 0; reg < 4; reg++)
#pragma unroll
      for (int g = 0; g < 4; g++)
        xvA[mt][g][reg] = xg[xgo[mt][reg] + (g << 8)];

#define LSTM_STEP(S_, P_, XC_, XN_)                                           \
  {                                                                           \
    if ((S_) == 0) {                                                          \
      _Pragma("unroll")                                                       \
      for (int i = 0; i < 4; i++) {                                           \
        int kc = kc4 + i;                                                     \
        float tmp[8];                                                         \
        const float* src = h0 + d * 8192 + sb * 256 + kc * 8;                 \
        _Pragma("unroll")                                                     \
        for (int j = 0; j < 8; j++) tmp[j] = src[j];                          \
        bf16x8 vhi, vlo;                                                      \
        split8(tmp, vhi, vlo);                                                \
        *(bf16x8*)&hfrag[0][0][fid_c[i]][pos_c[i] * 8] = vhi;                 \
        *(bf16x8*)&hfrag[0][1][fid_c[i]][pos_c[i] * 8] = vlo;                 \
      }                                                                       \
    } else {                                                                  \
      int fv = __hip_atomic_load(flags + fro, __ATOMIC_RELAXED,               \
                                 __HIP_MEMORY_SCOPE_AGENT);                   \
      while (!__all(fv == (S_))) {                                            \
        __builtin_amdgcn_s_sleep(1);                                          \
        fv = __hip_atomic_load(flags + fro, __ATOMIC_RELAXED,                 \
                               __HIP_MEMORY_SCOPE_AGENT);                     \
      }                                                                       \
      fro += 16;                                                              \
      unsigned long long v64[16];                                             \
      _Pragma("unroll")                                                       \
      for (int i = 0; i < 16; i++)                                            \
        v64[i] = __hip_atomic_load(hb64p[P_] + i, __ATOMIC_RELAXED,           \
                                   __HIP_MEMORY_SCOPE_AGENT);                 \
      _Pragma("unroll")                                                       \
      for (int i = 0; i < 4; i++) {                                           \
        u32x4 vh, vl;                                                         \
        _Pragma("unroll")                                                     \
        for (int k = 0; k < 4; k++) {                                         \
          unsigned int lo32 = (unsigned int)v64[i * 4 + k];                   \
          unsigned int hi32 = (unsigned int)(v64[i * 4 + k] >> 32);           \
          vh[k] = __builtin_amdgcn_perm(hi32, lo32, 0x07060302u);             \
          vl[k] = __builtin_amdgcn_perm(hi32, lo32, 0x05040100u);             \
        }                                                                     \
        *(u32x4*)&hfrag[P_][0][fid_c[i]][pos_c[i] * 8] = vh;                  \
        *(u32x4*)&hfrag[P_][1][fid_c[i]][pos_c[i] * 8] = vl;                  \
      }                                                                       \
    }                                                                         \
    /* pending h_seq store: previous step's h (no intra-kernel consumer) */   \
    if ((S_) > 0) {                                                           \
      _Pragma("unroll")                                                       \
      for (int mt = 0; mt < 2; mt++)                                          \
        _Pragma("unroll")                                                     \
        for (int reg = 0; reg < 4; reg++)                                     \
          h_seq[hso[mt][reg]] = hvp[mt][reg];                                 \
      _Pragma("unroll")                                                       \
      for (int mt = 0; mt < 2; mt++)                                          \
        _Pragma("unroll")                                                     \
        for (int reg = 0; reg < 4; reg++)                                     \
          hso[mt][reg] += sdelt;                                              \
    }                                                                         \
    /* xg prefetch for S_+1: issued AFTER the poll, drains under MFMA */      \
    if ((S_) < 511) {                                                         \
      _Pragma("unroll")                                                       \
      for (int mt = 0; mt < 2; mt++)                                          \
        _Pragma("unroll")                                                     \
        for (int reg = 0; reg < 4; reg++)                                     \
          xgo[mt][reg] += tdelt;                                              \
      _Pragma("unroll")                                                       \
      for (int mt = 0; mt < 2; mt++)                                          \
        _Pragma("unroll")                                                     \
        for (int reg = 0; reg < 4; reg++)                                     \
          _Pragma("unroll")                                                   \
          for (int g = 0; g < 4; g++)                                         \
            XN_[mt][g][reg] = xg[xgo[mt][reg] + (g << 8)];                    \
    }                                                                         \
    f32x4 acc[2][4];                                                          \
    _Pragma("unroll")                                                         \
    for (int mt = 0; mt < 2; mt++)                                            \
      _Pragma("unroll")                                                       \
      for (int g = 0; g < 4; g++)                                             \
        _Pragma("unroll")                                                     \
        for (int reg = 0; reg < 4; reg++)                                     \
          acc[mt][g][reg] = XC_[mt][g][reg];                                  \
    __syncthreads();                                                          \
    _Pragma("unroll")                                                         \
    for (int ks = 0; ks < 8; ks++) {                                          \
      int pos = (lane ^ ks) * 8;                                              \
      bf16x8 ahi0 = *(const bf16x8*)&hfrag[P_][0][ks][pos];                   \
      bf16x8 ahi1 = *(const bf16x8*)&hfrag[P_][0][8 + ks][pos];               \
      bf16x8 alo0 = *(const bf16x8*)&hfrag[P_][1][ks][pos];                   \
      bf16x8 alo1 = *(const bf16x8*)&hfrag[P_][1][8 + ks][pos];               \
      _Pragma("unroll")                                                       \
      for (int g = 0; g < 4; g++) {                                           \
        acc[0][g] = MFMA16(ahi0, wfh[g][ks], acc[0][g]);                      \
        acc[1][g] = MFMA16(ahi1, wfh[g][ks], acc[1][g]);                      \
        acc[0][g] = MFMA16(alo0, wfh[g][ks], acc[0][g]);                      \
        acc[1][g] = MFMA16(alo1, wfh[g][ks], acc[1][g]);                      \
        acc[0][g] = MFMA16(ahi0, wfl[g][ks], acc[0][g]);                      \
        acc[1][g] = MFMA16(ahi1, wfl[g][ks], acc[1][g]);                      \
      }                                                                       \
    }                                                                         \
    _Pragma("unroll")                                                         \
    for (int mt = 0; mt < 2; mt++)                                            \
      _Pragma("unroll")                                                       \
      for (int reg = 0; reg < 4; reg++) {                                     \
        float iv = sigm(acc[mt][0][reg]);                                     \
        float fg = sigm(acc[mt][1][reg]);                                     \
        float gv = tanh_f(acc[mt][2][reg]);                                   \
        float ov = sigm(acc[mt][3][reg]);                                     \
        float cn = fg * cst[mt][reg] + iv * gv;                               \
        cst[mt][reg] = cn;                                                    \
        float hn = ov * tanh_f(cn);                                           \
        hvp[mt][reg] = hn;                                                    \
        __bf16 hhi = (__bf16)hn;                                              \
        __bf16 hlo = (__bf16)(hn - (float)hhi);                               \
        unsigned int pack =                                                   \
            ((unsigned int)__builtin_bit_cast(unsigned short, hhi) << 16) |   \
            (unsigned int)__builtin_bit_cast(unsigned short, hlo);            \
        __hip_atomic_store(hx + ((P_) ? hwbase0 : hwbase1) + bof[mt][reg],    \
                           pack, __ATOMIC_RELAXED, __HIP_MEMORY_SCOPE_AGENT); \
      }                                                                       \
    asm volatile("s_waitcnt vmcnt(0)" ::: "memory");                          \
    if (lane == 0)                                                            \
      __hip_atomic_store(flags + fwo, (S_) + 1, __ATOMIC_RELAXED,             \
                         __HIP_MEMORY_SCOPE_AGENT);                           \
    fwo += 16;                                                                \
  }

  for (int s = 0; s < 512; s += 2) {
    LSTM_STEP(s,     0, xvA, xvB);
    LSTM_STEP(s + 1, 1, xvB, xvA);
  }
#undef LSTM_STEP

  // final pending store: h of step 511
#pragma unroll
  for (int mt = 0; mt < 2; mt++)
#pragma unroll
    for (int reg = 0; reg < 4; reg++)
      h_seq[hso[mt][reg]] = hvp[mt][reg];
}

// ---------------------------------------------------------------------------
// Kernel 3: feats[m][k] = h_seq[m][:] . W_out[k][:] + b_out[k]   (fp32)
// ---------------------------------------------------------------------------
__global__ __launch_bounds__(256) void feats_k(
    const float* __restrict__ h_seq, const float* __restrict__ W_out,
    const float* __restrict__ b_out, float* __restrict__ feats)
{
  int m = blockIdx.x * 4 + (threadIdx.x >> 6);
  int lane = threadIdx.x & 63;
  const float4* hp = (const float4*)(h_seq + (size_t)m * 512 + lane * 8);
  float4 a = hp[0], b2 = hp[1];
  float h[8] = {a.x, a.y, a.z, a.w, b2.x, b2.y, b2.z, b2.w};
#pragma unroll
  for (int k = 0; k < 12; k++) {
    const float4* wp = (const float4*)(W_out + k * 512 + lane * 8);
    float4 w0 = wp[0], w1 = wp[1];
    float w[8] = {w0.x, w0.y, w0.z, w0.w, w1.x, w1.y, w1.z, w1.w};
    float p = 0.0f;
#pragma unroll
    for (int j = 0; j < 8; j++) p += h[j] * w[j];
#pragma unroll
    for (int off = 32; off > 0; off >>= 1) p += __shfl_xor(p, off);
    if (lane == 0) feats[(size_t)m * 12 + k] = p + b_out[k];
  }
}

// ---------------------------------------------------------------------------
// Kernel 4: Viterbi per batch (one wave). First-max tie-break == jnp.argmax.
// ---------------------------------------------------------------------------
__global__ __launch_bounds__(64) void viterbi_k(
    const float* __restrict__ feats, const float* __restrict__ trans,
    float* __restrict__ terminal, int* __restrict__ best,
    float* __restrict__ out_path)
{
  const int b = blockIdx.x;
  const int lane = threadIdx.x;
  __shared__ unsigned char bp[512][12];
  float trow[12];
#pragma unroll
  for (int pv = 0; pv < 12; pv++)
    trow[pv] = (lane < 12) ? trans[lane * 12 + pv] : -10000.0f;
  float fv = (lane == 10) ? 0.0f : -10000.0f;   // START = 10
  for (int t = 0; t < 512; t++) {
    float bestv = -3.4e38f;
    int arg = 0;
#pragma unroll
    for (int pv = 0; pv < 12; pv++) {
      float sc = __shfl(fv, pv) + trow[pv];
      if (sc > bestv) { bestv = sc; arg = pv; }   // strict > keeps first max
    }
    float ft = (lane < 12) ? feats[(size_t)(b * 512 + t) * 12 + lane] : 0.0f;
    if (lane < 12) {
      bp[t][lane] = (unsigned char)arg;
      fv = bestv + ft;
    }
  }
  float term = fv + ((lane < 12) ? trans[11 * 12 + lane] : 0.0f);  // STOP = 11
  if (lane < 12) terminal[b * 12 + lane] = term;
  float v = (lane < 12) ? term : -3.4e38f;
  int idx = lane;
#pragma unroll
  for (int off = 8; off > 0; off >>= 1) {
    float ov = __shfl_down(v, off);
    int oi = __shfl_down(idx, off);
    if (ov > v || (ov == v && oi < idx)) { v = ov; idx = oi; }
  }
  int bidx = __shfl(idx, 0);
  __syncthreads();
  if (lane == 0) {
    best[b] = bidx;
    int tag = bidx;
    out_path[b * 512 + 511] = (float)bidx;
    for (int t = 511; t >= 1; t--) {
      tag = bp[t][tag];
      out_path[b * 512 + t - 1] = (float)tag;
    }
  }
}

// ---------------------------------------------------------------------------
// Kernel 5: path_score[i][j] = terminal[i][best[j]]
// ---------------------------------------------------------------------------
__global__ __launch_bounds__(256) void pscore_k(
    const float* __restrict__ terminal, const int* __restrict__ best,
    float* __restrict__ out)
{
  int idx = blockIdx.x * 256 + threadIdx.x;
  if (idx < 1024) {
    int i = idx >> 5, j = idx & 31;
    out[idx] = terminal[i * 12 + best[j]];
  }
}

// ---------------------------------------------------------------------------
extern "C" void kernel_launch(void* const* d_in, const int* in_sizes, int n_in,
                              void* d_out, int out_size, void* d_ws, size_t ws_size,
                              hipStream_t stream)
{
  const int*   sent  = (const int*)d_in[0];
  const float* embed = (const float*)d_in[1];
  const float* wih_f = (const float*)d_in[2];
  const float* whh_f = (const float*)d_in[3];
  const float* b_f   = (const float*)d_in[4];
  const float* wih_b = (const float*)d_in[5];
  const float* whh_b = (const float*)d_in[6];
  const float* b_b   = (const float*)d_in[7];
  const float* h0    = (const float*)d_in[8];
  const float* c0    = (const float*)d_in[9];
  const float* W_out = (const float*)d_in[10];
  const float* b_out = (const float*)d_in[11];
  const float* trans = (const float*)d_in[12];

  char* ws = (char*)d_ws;
  float*        xg    = (float*)(ws);                    // 134217728 B
  float*        h_seq = (float*)(ws + 134217728);        //  33554432 B
  float*        feats = (float*)(ws + 167772160);        //    786432 B
  unsigned int* hx    = (unsigned int*)(ws + 168558592); //    131072 B
  int*          flags = (int*)(ws + 168689664);          //     65536 B
  float*        term  = (float*)(ws + 168755200);        //      1536 B
  int*          best  = (int*)(ws + 168756736);          //       128 B

  float* outp = (float*)d_out;

  hipMemsetAsync(flags, 0, 2 * 512 * 16 * sizeof(int), stream);
  xg_gemm<<<dim3(128, 16), 256, 0, stream>>>(sent, embed, wih_f, wih_b, b_f, b_b, xg);
  lstm_rec<<<8, 256, 0, stream>>>(xg, whh_f, whh_b, h0, c0, h_seq, hx, flags);
  feats_k<<<4096, 256, 0, stream>>>(h_seq, W_out, b_out, feats);
  viterbi_k<<<32, 64, 0, stream>>>(feats, trans, term, best, outp + 1024);
  pscore_k<<<4, 256, 0, stream>>>(term, best, outp);
}

// Round 11
// 3855.886 us; speedup vs baseline: 1.3742x; 1.0756x over previous
//
#include <hip/hip_runtime.h>
#include <hip/hip_bf16.h>

// BiLSTM-CRF forward: B=32, T=512, E=512, H=256 (per dir), 4H=1024, K=12
// Inputs: fp32 (+ int32 sentence). Outputs fp32:
//   [0,1024)      path_score [32][32]
//   [1024,17408)  best_path  [32][512] (tags as fp32)
// R18 = exact revert to R15 (validated 3398us lstm_rec / 3856us total; best
// of session). R17's poll-first reorder regressed (3742us): it delayed the
// producer's flag publish by putting xg loads + h_seq stores into the
// publish-gating vmcnt(0) drain. LESSON (twice-confirmed): the producer's
// publish latency is the critical path — keep the vmem queue empty at the
// PUBLISH point, not the poll point. R15's order does exactly that:
//   poll -> hx loads -> perm-unpack -> stage -> barrier -> MFMA -> epilogue
//   -> hx stores -> vmcnt(0) -> flag -> h_seq stores -> xg prefetch.
// Falsified protocol variants (do not revisit): tagged value+validity words
// (R8/R16: LLC rescans + u64 traffic), sc0/local-L2 exchange (R9: stale
// lines), 1MB-strided mailbox (R11: LLC channel aliasing), flag RMW->store
// (R12: null), intra-step phase split (R13: phase compute < RT), weights
// consolidation to 16 waves/CU (R14: register spill at >1 wave/SIMD).

typedef __attribute__((ext_vector_type(8))) __bf16 bf16x8;
typedef __attribute__((ext_vector_type(4))) float  f32x4;
typedef __attribute__((ext_vector_type(4))) unsigned int u32x4;

#define MFMA16(a, b, c) __builtin_amdgcn_mfma_f32_16x16x32_bf16((a), (b), (c), 0, 0, 0)

__device__ __forceinline__ float sigm(float x) { return 1.0f / (1.0f + __expf(-x)); }
__device__ __forceinline__ float tanh_f(float x) {
  x = fminf(fmaxf(x, -15.0f), 15.0f);
  float e = __expf(2.0f * x);
  return (e - 1.0f) / (e + 1.0f);
}

__device__ __forceinline__ void split8(const float* v, bf16x8& hi, bf16x8& lo) {
#pragma unroll
  for (int j = 0; j < 8; j++) {
    __bf16 h = (__bf16)v[j];
    hi[j] = h;
    lo[j] = (__bf16)(v[j] - (float)h);
  }
}

// ---------------------------------------------------------------------------
// Kernel 1: xg[m=(b,t)][n=(dir,gate,unit)] = embed[sent[m]].w_ih[n] + bias[n]
// M=16384, N=2048, K=512. 128x128 tile/WG, 4 waves 2x2, 3-term hi/lo MFMA.
// ---------------------------------------------------------------------------
__global__ __launch_bounds__(256) void xg_gemm(
    const int* __restrict__ sent, const float* __restrict__ embed,
    const float* __restrict__ wih_f, const float* __restrict__ wih_b,
    const float* __restrict__ bias_f, const float* __restrict__ bias_b,
    float* __restrict__ xg)
{
  __shared__ __bf16 Ah[128][40], Al[128][40];  // 32 k + 8 pad
  __shared__ __bf16 Bh[128][40], Bl[128][40];
  __shared__ int toks[128];
  const int tid = threadIdx.x;
  const int m0 = blockIdx.x * 128, n0 = blockIdx.y * 128;
  if (tid < 128) toks[tid] = sent[m0 + tid];
  const int wave = tid >> 6, lane = tid & 63, q = lane >> 4, c = lane & 15;
  const int wy = wave >> 1, wx = wave & 1;
  f32x4 acc[4][4];
  for (int mt = 0; mt < 4; mt++)
    for (int nt = 0; nt < 4; nt++)
      acc[mt][nt] = f32x4{0.0f, 0.0f, 0.0f, 0.0f};
  __syncthreads();

  for (int k0 = 0; k0 < 512; k0 += 32) {
#pragma unroll
    for (int i = 0; i < 2; i++) {
      int ch = tid + (i << 8);
      int r = ch >> 2, kc = ch & 3;
      float tmp[8];
      const float* asrc = embed + (size_t)toks[r] * 512 + k0 + kc * 8;
#pragma unroll
      for (int j = 0; j < 8; j++) tmp[j] = asrc[j];
      bf16x8 hi, lo;
      split8(tmp, hi, lo);
      *(bf16x8*)&Ah[r][kc * 8] = hi;
      *(bf16x8*)&Al[r][kc * 8] = lo;
      int n = n0 + r;
      const float* wsrc = (n < 1024) ? (wih_f + (size_t)n * 512)
                                     : (wih_b + (size_t)(n - 1024) * 512);
#pragma unroll
      for (int j = 0; j < 8; j++) tmp[j] = wsrc[k0 + kc * 8 + j];
      split8(tmp, hi, lo);
      *(bf16x8*)&Bh[r][kc * 8] = hi;
      *(bf16x8*)&Bl[r][kc * 8] = lo;
    }
    __syncthreads();
    bf16x8 ah[4], al[4], bh[4], bl[4];
#pragma unroll
    for (int t4 = 0; t4 < 4; t4++) {
      int ar = wy * 64 + t4 * 16 + c, br = wx * 64 + t4 * 16 + c;
      ah[t4] = *(const bf16x8*)&Ah[ar][q * 8];
      al[t4] = *(const bf16x8*)&Al[ar][q * 8];
      bh[t4] = *(const bf16x8*)&Bh[br][q * 8];
      bl[t4] = *(const bf16x8*)&Bl[br][q * 8];
    }
#pragma unroll
    for (int mt = 0; mt < 4; mt++)
#pragma unroll
      for (int nt = 0; nt < 4; nt++) {
        acc[mt][nt] = MFMA16(ah[mt], bh[nt], acc[mt][nt]);
        acc[mt][nt] = MFMA16(al[mt], bh[nt], acc[mt][nt]);
        acc[mt][nt] = MFMA16(ah[mt], bl[nt], acc[mt][nt]);
      }
    __syncthreads();
  }

#pragma unroll
  for (int nt = 0; nt < 4; nt++) {
    int n = n0 + wx * 64 + nt * 16 + c;
    float bval = (n < 1024) ? bias_f[n] : bias_b[n - 1024];
#pragma unroll
    for (int mt = 0; mt < 4; mt++) {
      int mbase = m0 + wy * 64 + mt * 16 + q * 4;
#pragma unroll
      for (int reg = 0; reg < 4; reg++)
        xg[(size_t)(mbase + reg) * 2048 + n] = acc[mt][nt][reg] + bval;
    }
  }
}

// ---------------------------------------------------------------------------
// Kernel 2: both LSTM recurrences. 8 blocks: blk = d*4 + hs. R12 protocol.
// ---------------------------------------------------------------------------
__global__ __launch_bounds__(256, 1) void lstm_rec(
    const float* __restrict__ xg,
    const float* __restrict__ whh_f, const float* __restrict__ whh_b,
    const float* __restrict__ h0, const float* __restrict__ c0,
    float* __restrict__ h_seq,     // [32][512][512]: cols 0-255 fwd, 256-511 bwd
    unsigned int* __restrict__ hx, // [dir][parity][32][256] packed hi/lo bf16
    int* __restrict__ flags)       // [dir][step][16 waves]
{
  const int blk = blockIdx.x;
  const int d = blk >> 2, hs = blk & 3;
  const int tid = threadIdx.x;
  const int wave = tid >> 6, lane = tid & 63, q = lane >> 4, c = lane & 15;
  const float* __restrict__ whh = d ? whh_b : whh_f;

  __shared__ __bf16 hfrag[2][2][16][512];  // [parity][hi/lo][frag][xor-swizzled]

  bf16x8 wfh[4][8], wfl[4][8];
#pragma unroll
  for (int g = 0; g < 4; g++) {
    int row = g * 256 + hs * 64 + wave * 16 + c;   // w_hh row (gate-major)
    const float* wr = whh + (size_t)row * 256;
#pragma unroll
    for (int ks = 0; ks < 8; ks++) {
      float tmp[8];
#pragma unroll
      for (int j = 0; j < 8; j++) tmp[j] = wr[ks * 32 + q * 8 + j];
      split8(tmp, wfh[g][ks], wfl[g][ks]);
    }
  }
  const int ug = hs * 64 + wave * 16 + c;
  float cst[2][4];
#pragma unroll
  for (int mt = 0; mt < 2; mt++)
#pragma unroll
    for (int reg = 0; reg < 4; reg++)
      cst[mt][reg] = c0[d * 8192 + (mt * 16 + q * 4 + reg) * 256 + ug];

  const int sb = tid >> 3;            // staging: batch row
  const int kc4 = (tid & 7) * 4;      // staging: first 8-elem chunk

  // staging LDS indices are per-thread constants
  int fid_c[4], pos_c[4];
#pragma unroll
  for (int i = 0; i < 4; i++) {
    int kc = kc4 + i;
    fid_c[i] = ((sb >> 4) << 3) + (kc >> 2);
    pos_c[i] = ((((kc & 3) << 4) + (sb & 15)) ^ (fid_c[i] & 7));
  }

  // exchange read bases (per parity)
  const unsigned long long* hb64p[2];
  hb64p[0] = (const unsigned long long*)(hx + ((size_t)((d * 2 + 0) * 32 + sb)) * 256 + kc4 * 8);
  hb64p[1] = (const unsigned long long*)(hx + ((size_t)((d * 2 + 1) * 32 + sb)) * 256 + kc4 * 8);
  // exchange write bases (per parity) + per-(mt,reg) batch offsets
  const int hwbase0 = (d * 2 + 0) * 32 * 256 + ug;
  const int hwbase1 = (d * 2 + 1) * 32 * 256 + ug;
  int bof[2][4];
#pragma unroll
  for (int mt = 0; mt < 2; mt++)
#pragma unroll
    for (int reg = 0; reg < 4; reg++)
      bof[mt][reg] = (mt * 16 + q * 4 + reg) * 256;

  int fro = (d * 512) * 16 + (lane & 15);    // flag line polled at step s (holds s-1)
  int fwo = (d * 512) * 16 + hs * 4 + wave;  // flag word written at step s

  const int t0 = d ? 511 : 0;
  const int tdelt = d ? -2048 : 2048;        // xg element-offset delta per step
  const int sdelt = d ? -512 : 512;          // h_seq element-offset delta per step

  int xgo[2][4], hso[2][4];
#pragma unroll
  for (int mt = 0; mt < 2; mt++)
#pragma unroll
    for (int reg = 0; reg < 4; reg++) {
      int b = mt * 16 + q * 4 + reg;
      xgo[mt][reg] = (b * 512 + t0) * 2048 + (d << 10) + ug;
      hso[mt][reg] = (b * 512 + t0) * 512 + (d << 8) + ug;
    }

  float xvA[2][4][4], xvB[2][4][4];
#pragma unroll
  for (int mt = 0; mt < 2; mt++)
#pragma unroll
    for (int reg = 0; reg < 4; reg++)
#pragma unroll
      for (int g = 0; g < 4; g++)
        xvA[mt][g][reg] = xg[xgo[mt][reg] + (g << 8)];

#define LSTM_STEP(S_, P_, XC_, XN_)                                           \
  {                                                                           \
    if ((S_) == 0) {                                                          \
      _Pragma("unroll")                                                       \
      for (int i = 0; i < 4; i++) {                                           \
        int kc = kc4 + i;                                                     \
        float tmp[8];                                                         \
        const float* src = h0 + d * 8192 + sb * 256 + kc * 8;                 \
        _Pragma("unroll")                                                     \
        for (int j = 0; j < 8; j++) tmp[j] = src[j];                          \
        bf16x8 vhi, vlo;                                                      \
        split8(tmp, vhi, vlo);                                                \
        *(bf16x8*)&hfrag[0][0][fid_c[i]][pos_c[i] * 8] = vhi;                 \
        *(bf16x8*)&hfrag[0][1][fid_c[i]][pos_c[i] * 8] = vlo;                 \
      }                                                                       \
    } else {                                                                  \
      int fv = __hip_atomic_load(flags + fro, __ATOMIC_RELAXED,               \
                                 __HIP_MEMORY_SCOPE_AGENT);                   \
      while (!__all(fv == (S_))) {                                            \
        __builtin_amdgcn_s_sleep(1);                                          \
        fv = __hip_atomic_load(flags + fro, __ATOMIC_RELAXED,                 \
                               __HIP_MEMORY_SCOPE_AGENT);                     \
      }                                                                       \
      fro += 16;                                                              \
      unsigned long long v64[16];                                             \
      _Pragma("unroll")                                                       \
      for (int i = 0; i < 16; i++)                                            \
        v64[i] = __hip_atomic_load(hb64p[P_] + i, __ATOMIC_RELAXED,           \
                                   __HIP_MEMORY_SCOPE_AGENT);                 \
      _Pragma("unroll")                                                       \
      for (int i = 0; i < 4; i++) {                                           \
        u32x4 vh, vl;                                                         \
        _Pragma("unroll")                                                     \
        for (int k = 0; k < 4; k++) {                                         \
          unsigned int lo32 = (unsigned int)v64[i * 4 + k];                   \
          unsigned int hi32 = (unsigned int)(v64[i * 4 + k] >> 32);           \
          vh[k] = __builtin_amdgcn_perm(hi32, lo32, 0x07060302u);             \
          vl[k] = __builtin_amdgcn_perm(hi32, lo32, 0x05040100u);             \
        }                                                                     \
        *(u32x4*)&hfrag[P_][0][fid_c[i]][pos_c[i] * 8] = vh;                  \
        *(u32x4*)&hfrag[P_][1][fid_c[i]][pos_c[i] * 8] = vl;                  \
      }                                                                       \
    }                                                                         \
    f32x4 acc[2][4];                                                          \
    _Pragma("unroll")                                                         \
    for (int mt = 0; mt < 2; mt++)                                            \
      _Pragma("unroll")                                                       \
      for (int g = 0; g < 4; g++)                                             \
        _Pragma("unroll")                                                     \
        for (int reg = 0; reg < 4; reg++)                                     \
          acc[mt][g][reg] = XC_[mt][g][reg];                                  \
    __syncthreads();                                                          \
    _Pragma("unroll")                                                         \
    for (int ks = 0; ks < 8; ks++) {                                          \
      int pos = (lane ^ ks) * 8;                                              \
      bf16x8 ahi0 = *(const bf16x8*)&hfrag[P_][0][ks][pos];                   \
      bf16x8 ahi1 = *(const bf16x8*)&hfrag[P_][0][8 + ks][pos];               \
      bf16x8 alo0 = *(const bf16x8*)&hfrag[P_][1][ks][pos];                   \
      bf16x8 alo1 = *(const bf16x8*)&hfrag[P_][1][8 + ks][pos];               \
      _Pragma("unroll")                                                       \
      for (int g = 0; g < 4; g++) {                                           \
        acc[0][g] = MFMA16(ahi0, wfh[g][ks], acc[0][g]);                      \
        acc[1][g] = MFMA16(ahi1, wfh[g][ks], acc[1][g]);                      \
        acc[0][g] = MFMA16(alo0, wfh[g][ks], acc[0][g]);                      \
        acc[1][g] = MFMA16(alo1, wfh[g][ks], acc[1][g]);                      \
        acc[0][g] = MFMA16(ahi0, wfl[g][ks], acc[0][g]);                      \
        acc[1][g] = MFMA16(ahi1, wfl[g][ks], acc[1][g]);                      \
      }                                                                       \
    }                                                                         \
    float hv[2][4];                                                           \
    _Pragma("unroll")                                                         \
    for (int mt = 0; mt < 2; mt++)                                            \
      _Pragma("unroll")                                                       \
      for (int reg = 0; reg < 4; reg++) {                                     \
        float iv = sigm(acc[mt][0][reg]);                                     \
        float fg = sigm(acc[mt][1][reg]);                                     \
        float gv = tanh_f(acc[mt][2][reg]);                                   \
        float ov = sigm(acc[mt][3][reg]);                                     \
        float cn = fg * cst[mt][reg] + iv * gv;                               \
        cst[mt][reg] = cn;                                                    \
        float hn = ov * tanh_f(cn);                                           \
        hv[mt][reg] = hn;                                                     \
        __bf16 hhi = (__bf16)hn;                                              \
        __bf16 hlo = (__bf16)(hn - (float)hhi);                               \
        unsigned int pack =                                                   \
            ((unsigned int)__builtin_bit_cast(unsigned short, hhi) << 16) |   \
            (unsigned int)__builtin_bit_cast(unsigned short, hlo);            \
        __hip_atomic_store(hx + ((P_) ? hwbase0 : hwbase1) + bof[mt][reg],    \
                           pack, __ATOMIC_RELAXED, __HIP_MEMORY_SCOPE_AGENT); \
      }                                                                       \
    asm volatile("s_waitcnt vmcnt(0)" ::: "memory");                          \
    if (lane == 0)                                                            \
      __hip_atomic_store(flags + fwo, (S_) + 1, __ATOMIC_RELAXED,             \
                         __HIP_MEMORY_SCOPE_AGENT);                           \
    fwo += 16;                                                                \
    _Pragma("unroll")                                                         \
    for (int mt = 0; mt < 2; mt++)                                            \
      _Pragma("unroll")                                                       \
      for (int reg = 0; reg < 4; reg++)                                       \
        h_seq[hso[mt][reg]] = hv[mt][reg];                                    \
    if ((S_) < 511) {                                                         \
      _Pragma("unroll")                                                       \
      for (int mt = 0; mt < 2; mt++)                                          \
        _Pragma("unroll")                                                     \
        for (int reg = 0; reg < 4; reg++) {                                   \
          xgo[mt][reg] += tdelt;                                              \
          hso[mt][reg] += sdelt;                                              \
        }                                                                     \
      _Pragma("unroll")                                                       \
      for (int mt = 0; mt < 2; mt++)                                          \
        _Pragma("unroll")                                                     \
        for (int reg = 0; reg < 4; reg++)                                     \
          _Pragma("unroll")                                                   \
          for (int g = 0; g < 4; g++)                                         \
            XN_[mt][g][reg] = xg[xgo[mt][reg] + (g << 8)];                    \
    }                                                                         \
  }

  for (int s = 0; s < 512; s += 2) {
    LSTM_STEP(s,     0, xvA, xvB);
    LSTM_STEP(s + 1, 1, xvB, xvA);
  }
#undef LSTM_STEP
}

// ---------------------------------------------------------------------------
// Kernel 3: feats[m][k] = h_seq[m][:] . W_out[k][:] + b_out[k]   (fp32)
// ---------------------------------------------------------------------------
__global__ __launch_bounds__(256) void feats_k(
    const float* __restrict__ h_seq, const float* __restrict__ W_out,
    const float* __restrict__ b_out, float* __restrict__ feats)
{
  int m = blockIdx.x * 4 + (threadIdx.x >> 6);
  int lane = threadIdx.x & 63;
  const float4* hp = (const float4*)(h_seq + (size_t)m * 512 + lane * 8);
  float4 a = hp[0], b2 = hp[1];
  float h[8] = {a.x, a.y, a.z, a.w, b2.x, b2.y, b2.z, b2.w};
#pragma unroll
  for (int k = 0; k < 12; k++) {
    const float4* wp = (const float4*)(W_out + k * 512 + lane * 8);
    float4 w0 = wp[0], w1 = wp[1];
    float w[8] = {w0.x, w0.y, w0.z, w0.w, w1.x, w1.y, w1.z, w1.w};
    float p = 0.0f;
#pragma unroll
    for (int j = 0; j < 8; j++) p += h[j] * w[j];
#pragma unroll
    for (int off = 32; off > 0; off >>= 1) p += __shfl_xor(p, off);
    if (lane == 0) feats[(size_t)m * 12 + k] = p + b_out[k];
  }
}

// ---------------------------------------------------------------------------
// Kernel 4: Viterbi per batch (one wave). First-max tie-break == jnp.argmax.
// ---------------------------------------------------------------------------
__global__ __launch_bounds__(64) void viterbi_k(
    const float* __restrict__ feats, const float* __restrict__ trans,
    float* __restrict__ terminal, int* __restrict__ best,
    float* __restrict__ out_path)
{
  const int b = blockIdx.x;
  const int lane = threadIdx.x;
  __shared__ unsigned char bp[512][12];
  float trow[12];
#pragma unroll
  for (int pv = 0; pv < 12; pv++)
    trow[pv] = (lane < 12) ? trans[lane * 12 + pv] : -10000.0f;
  float fv = (lane == 10) ? 0.0f : -10000.0f;   // START = 10
  for (int t = 0; t < 512; t++) {
    float bestv = -3.4e38f;
    int arg = 0;
#pragma unroll
    for (int pv = 0; pv < 12; pv++) {
      float sc = __shfl(fv, pv) + trow[pv];
      if (sc > bestv) { bestv = sc; arg = pv; }   // strict > keeps first max
    }
    float ft = (lane < 12) ? feats[(size_t)(b * 512 + t) * 12 + lane] : 0.0f;
    if (lane < 12) {
      bp[t][lane] = (unsigned char)arg;
      fv = bestv + ft;
    }
  }
  float term = fv + ((lane < 12) ? trans[11 * 12 + lane] : 0.0f);  // STOP = 11
  if (lane < 12) terminal[b * 12 + lane] = term;
  float v = (lane < 12) ? term : -3.4e38f;
  int idx = lane;
#pragma unroll
  for (int off = 8; off > 0; off >>= 1) {
    float ov = __shfl_down(v, off);
    int oi = __shfl_down(idx, off);
    if (ov > v || (ov == v && oi < idx)) { v = ov; idx = oi; }
  }
  int bidx = __shfl(idx, 0);
  __syncthreads();
  if (lane == 0) {
    best[b] = bidx;
    int tag = bidx;
    out_path[b * 512 + 511] = (float)bidx;
    for (int t = 511; t >= 1; t--) {
      tag = bp[t][tag];
      out_path[b * 512 + t - 1] = (float)tag;
    }
  }
}

// ---------------------------------------------------------------------------
// Kernel 5: path_score[i][j] = terminal[i][best[j]]
// ---------------------------------------------------------------------------
__global__ __launch_bounds__(256) void pscore_k(
    const float* __restrict__ terminal, const int* __restrict__ best,
    float* __restrict__ out)
{
  int idx = blockIdx.x * 256 + threadIdx.x;
  if (idx < 1024) {
    int i = idx >> 5, j = idx & 31;
    out[idx] = terminal[i * 12 + best[j]];
  }
}

// ---------------------------------------------------------------------------
extern "C" void kernel_launch(void* const* d_in, const int* in_sizes, int n_in,
                              void* d_out, int out_size, void* d_ws, size_t ws_size,
                              hipStream_t stream)
{
  const int*   sent  = (const int*)d_in[0];
  const float* embed = (const float*)d_in[1];
  const float* wih_f = (const float*)d_in[2];
  const float* whh_f = (const float*)d_in[3];
  const float* b_f   = (const float*)d_in[4];
  const float* wih_b = (const float*)d_in[5];
  const float* whh_b = (const float*)d_in[6];
  const float* b_b   = (const float*)d_in[7];
  const float* h0    = (const float*)d_in[8];
  const float* c0    = (const float*)d_in[9];
  const float* W_out = (const float*)d_in[10];
  const float* b_out = (const float*)d_in[11];
  const float* trans = (const float*)d_in[12];

  char* ws = (char*)d_ws;
  float*        xg    = (float*)(ws);                    // 134217728 B
  float*        h_seq = (float*)(ws + 134217728);        //  33554432 B
  float*        feats = (float*)(ws + 167772160);        //    786432 B
  unsigned int* hx    = (unsigned int*)(ws + 168558592); //    131072 B
  int*          flags = (int*)(ws + 168689664);          //     65536 B
  float*        term  = (float*)(ws + 168755200);        //      1536 B
  int*          best  = (int*)(ws + 168756736);          //       128 B

  float* outp = (float*)d_out;

  hipMemsetAsync(flags, 0, 2 * 512 * 16 * sizeof(int), stream);
  xg_gemm<<<dim3(128, 16), 256, 0, stream>>>(sent, embed, wih_f, wih_b, b_f, b_b, xg);
  lstm_rec<<<8, 256, 0, stream>>>(xg, whh_f, whh_b, h0, c0, h_seq, hx, flags);
  feats_k<<<4096, 256, 0, stream>>>(h_seq, W_out, b_out, feats);
  viterbi_k<<<32, 64, 0, stream>>>(feats, trans, term, best, outp + 1024);
  pscore_k<<<4, 256, 0, stream>>>(term, best, outp);
}